// Round 8
// baseline (156.796 us; speedup 1.0000x reference)
//
#include <hip/hip_runtime.h>
#include <hip/hip_bf16.h>

// out[b,c,y,x] = sum_{i,j} f[b,c,y+i-3,x+j-3] * ker[b,i,j,y,x]
// Single-wave blocks (64 thr) -> NO barriers (wave-synchronous LDS).
// Thread = (tx 0..15, ty 0..3), owns 2 y-pixels x 8 channels per iter.
// Taps: bf16 y-pair packed, 49 u32 VGPRs. Features: bf16 ch-pair packed in
// LDS [row][px][c8], window 14 rows x 24 px, rebuilt per channel-octet.

#define BATCH 4
#define CHAN 96
#define HW_ 256
#define HWPIX 65536
#define KS 7
#define TQX 16
#define TQY 8
#define NTHR 64
#define CG 8
#define NCQ (CHAN / CG)        // 12
#define WROWS 14               // TQY + 6
#define WPX 24                 // TQX + 8 (origin gx0-4)
#define ROWU32 (WPX * 4)       // 96 u32 per row
#define LDSU32 (16 * ROWU32)   // padded to 16 rows (rows 14-15 = spill pad)
#define SLOTS (WROWS * 24)     // 336 write slots (6 xquads x 4 ch-pairs)
#define SPT 6

typedef __attribute__((ext_vector_type(4))) unsigned u32x4;

static __device__ __forceinline__ unsigned pkbf(float a, float b) {
    union { __hip_bfloat162 h; unsigned u; } c;
    c.h = __float22bfloat162_rn(make_float2(a, b));
    return c.u;                 // lo = bf(a), hi = bf(b)
}
static __device__ __forceinline__ float blo(unsigned u) {
    union { unsigned v; float f; } c; c.v = u << 16; return c.f;
}
static __device__ __forceinline__ float bhi(unsigned u) {
    union { unsigned v; float f; } c; c.v = u & 0xffff0000u; return c.f;
}

__global__ __launch_bounds__(NTHR, 3)
void svconv_v8(const float* __restrict__ K_, const float* __restrict__ F_,
               float* __restrict__ O_) {
    __shared__ unsigned lds[LDSU32];   // 6144 B

    // XCD-chunked swizzle: grid 2048 = 8 XCD x 256; neighbors share halo/L2
    const unsigned bid0 = blockIdx.x;
    const unsigned bid = (bid0 & 7) * 256 + (bid0 >> 3);
    const int xt = bid & 15, yt = (bid >> 4) & 31, b = bid >> 9;

    const int tid = threadIdx.x;
    const int tx = tid & 15, ty = tid >> 4;
    const int gx0 = xt * TQX, y0b = yt * TQY;
    const int gx = gx0 + tx;
    const int y0 = y0b + ty * 2;

    // ---- taps: 49 u32, bf16 pair (y0, y0+1) per (i,j) ----
    unsigned kp[KS * KS];
#pragma unroll
    for (int i = 0; i < KS; ++i)
#pragma unroll
        for (int j = 0; j < KS; ++j) {
            const float* kpp = K_ + ((((size_t)b * KS + i) * KS + j) * HW_ + y0) * HW_ + gx;
            kp[i * KS + j] = pkbf(kpp[0], kpp[HW_]);
        }

    // ---- staging slot precompute (iteration-invariant) ----
    // slot idx = tid + 64k: p = idx&3 (ch-pair), xq = (idx>>2)%6, row = idx/24
    int goff[SPT];        // clamped global offset (ch 2p base)
    unsigned ldso[SPT];   // u32 index of element jj=0
    unsigned msk[SPT];    // bit jj: element valid
#pragma unroll
    for (int k = 0; k < SPT; ++k) {
        const int idx = tid + NTHR * k;
        const int p = idx & 3, xq = (idx >> 2) % 6, row = idx / 24;
        const int fy = y0b - 3 + row;
        const int fxb = gx0 - 4 + xq * 4;
        const int fyc = fy < 0 ? 0 : (fy > HW_ - 1 ? HW_ - 1 : fy);
        const int fxc = fxb < 0 ? 0 : (fxb > HW_ - 4 ? HW_ - 4 : fxb);
        goff[k] = 2 * p * HWPIX + fyc * HW_ + fxc;
        ldso[k] = (unsigned)((row * WPX + xq * 4) * 4 + p);
        unsigned m = 0;
        if ((unsigned)fy < (unsigned)HW_ && idx < SLOTS) {
#pragma unroll
            for (int jj = 0; jj < 4; ++jj)
                if ((unsigned)(fxb + jj) < (unsigned)HW_) m |= 1u << jj;
        }
        msk[k] = m;
    }

    const float* Fb = F_ + (size_t)b * CHAN * HWPIX;
    float* ob = O_ + (size_t)b * CHAN * HWPIX + (size_t)y0 * HW_ + gx;
    const int ty2 = ty * 2;

    // ---- prologue: issue loads for channel-octet 0 ----
    float4 rA[SPT], rB[SPT];
#pragma unroll
    for (int k = 0; k < SPT; ++k) {
        rA[k] = *(const float4*)(Fb + goff[k]);
        rB[k] = *(const float4*)(Fb + goff[k] + HWPIX);
    }

#pragma unroll 1
    for (int cq = 0; cq < NCQ; ++cq) {
        // ---- pack + write staged octet (wave-synchronous; no barrier) ----
#pragma unroll
        for (int k = 0; k < SPT; ++k) {
            unsigned w0 = pkbf(rA[k].x, rB[k].x);
            unsigned w1 = pkbf(rA[k].y, rB[k].y);
            unsigned w2 = pkbf(rA[k].z, rB[k].z);
            unsigned w3 = pkbf(rA[k].w, rB[k].w);
            w0 = (msk[k] & 1u) ? w0 : 0u;
            w1 = (msk[k] & 2u) ? w1 : 0u;
            w2 = (msk[k] & 4u) ? w2 : 0u;
            w3 = (msk[k] & 8u) ? w3 : 0u;
            lds[ldso[k]]      = w0;
            lds[ldso[k] + 4]  = w1;
            lds[ldso[k] + 8]  = w2;
            lds[ldso[k] + 12] = w3;
        }

        // ---- issue next octet's loads; fly under compute (T14) ----
        if (cq + 1 < NCQ) {
            const float* Fp = Fb + (size_t)(cq + 1) * CG * HWPIX;
#pragma unroll
            for (int k = 0; k < SPT; ++k) {
                rA[k] = *(const float4*)(Fp + goff[k]);
                rB[k] = *(const float4*)(Fp + goff[k] + HWPIX);
            }
        }

        // ---- compute: 8 window rows x 7 taps, 8 channels, 2 y-outputs ----
        float acc0[CG] = {0.f, 0.f, 0.f, 0.f, 0.f, 0.f, 0.f, 0.f};
        float acc1[CG] = {0.f, 0.f, 0.f, 0.f, 0.f, 0.f, 0.f, 0.f};
#pragma unroll
        for (int roff = 0; roff < TQY / 4 + 6; ++roff) {   // 8 rows
            const int rb = (ty2 + roff) * ROWU32;
#pragma unroll
            for (int dx = 0; dx < KS; ++dx) {
                const int px = tx + 1 + dx;
                const u32x4 v = *(const u32x4*)&lds[rb + px * 4];
                float f[CG];
                f[0] = blo(v.x); f[1] = bhi(v.x);
                f[2] = blo(v.y); f[3] = bhi(v.y);
                f[4] = blo(v.z); f[5] = bhi(v.z);
                f[6] = blo(v.w); f[7] = bhi(v.w);
                if (roff <= 6) {
                    const float t = blo(kp[roff * KS + dx]);   // s=0, i=roff
#pragma unroll
                    for (int c = 0; c < CG; ++c) acc0[c] += f[c] * t;
                }
                if (roff >= 1) {
                    const float t = bhi(kp[(roff - 1) * KS + dx]);  // s=1
#pragma unroll
                    for (int c = 0; c < CG; ++c) acc1[c] += f[c] * t;
                }
            }
        }

        // ---- stores (16 lanes consecutive in x per segment) ----
        float* op = ob + (size_t)cq * CG * HWPIX;
#pragma unroll
        for (int c = 0; c < CG; ++c) {
            op[(size_t)c * HWPIX]       = acc0[c];
            op[(size_t)c * HWPIX + HW_] = acc1[c];
        }
    }
}

extern "C" void kernel_launch(void* const* d_in, const int* in_sizes, int n_in,
                              void* d_out, int out_size, void* d_ws, size_t ws_size,
                              hipStream_t stream) {
    const float* kernels  = (const float*)d_in[0];  // [4,7,7,256,256]
    const float* features = (const float*)d_in[1];  // [4,96,256,256]
    float* out = (float*)d_out;                     // [4,96,256,256]

    dim3 grid(2048);   // (16 xt) x (32 yt) x (4 b), decoded after XCD swizzle
    dim3 block(NTHR);
    svconv_v8<<<grid, block, 0, stream>>>(kernels, features, out);
}

// Round 9
// 113.667 us; speedup vs baseline: 1.3794x; 1.3794x over previous
//
#include <hip/hip_runtime.h>
#include <hip/hip_bf16.h>

// out[b,c,y,x] = sum_{i,j} f[b,c,y+i-3,x+j-3] * ker[b,i,j,y,x]
// Single-wave blocks (64 thr), wave-synchronous LDS (no barriers).
// Thread = (tx 0..31, ty 0..1): one x-column, one y-pair, 8 channels/iter.
// LDS granule = 16B = 8 bf16 ch-pairs at one (row,px); granule-gather staging
// (8 coalesced dword loads -> 1 thread-linear ds_write_b128, conflict-free).
// Taps: 49 u32 (bf16 y-pair packed). 12 channel-octet iterations.

#define BATCH 4
#define CHAN 96
#define HW_ 256
#define HWPIX 65536
#define KS 7
#define TW 32
#define THT 4
#define NTHR 64
#define CG 8
#define NCQ (CHAN / CG)      // 12
#define WROWS 10             // THT + 6
#define WPX 38               // TW + 6 (origin gx0-3)
#define GRAN (WROWS * WPX)   // 380
#define GRANP 384            // LDS granules (pad; idle slots land in 380..383)
#define SPT 6                // ceil(GRAN/64)

typedef __attribute__((ext_vector_type(4))) unsigned u32x4;

static __device__ __forceinline__ unsigned pkbf(float a, float b) {
    union { __hip_bfloat162 h; unsigned u; } c;
    c.h = __float22bfloat162_rn(make_float2(a, b));
    return c.u;                 // lo = bf(a), hi = bf(b)
}
static __device__ __forceinline__ float blo(unsigned u) {
    union { unsigned v; float f; } c; c.v = u << 16; return c.f;
}
static __device__ __forceinline__ float bhi(unsigned u) {
    union { unsigned v; float f; } c; c.v = u & 0xffff0000u; return c.f;
}

__global__ __launch_bounds__(NTHR)
void svconv_v9(const float* __restrict__ K_, const float* __restrict__ F_,
               float* __restrict__ O_) {
    __shared__ u32x4 lds[GRANP];   // 6144 B

    // XCD-chunked swizzle (2048 % 8 == 0 -> bijective). Consecutive bids in a
    // chunk are consecutive yt -> y-halo neighbors share one XCD's L2.
    const unsigned bid0 = blockIdx.x;
    const unsigned bid = (bid0 & 7) * 256 + (bid0 >> 3);
    const int yt = bid & 63, xt = (bid >> 6) & 7, b = bid >> 9;

    const int lane = threadIdx.x;
    const int tx = lane & 31, ty = lane >> 5;
    const int gx0 = xt * TW, y0b = yt * THT;
    const int gx = gx0 + tx;
    const int y0 = y0b + 2 * ty;          // y0, y0+1 owned by this thread

    // ---- taps: 49 u32, bf16 (y0, y0+1) pair per (i,j) ----
    unsigned kp[KS * KS];
#pragma unroll
    for (int i = 0; i < KS; ++i)
#pragma unroll
        for (int j = 0; j < KS; ++j) {
            const float* kpp =
                K_ + ((((size_t)b * KS + i) * KS + j) * HW_ + y0) * HW_ + gx;
            kp[i * KS + j] = pkbf(kpp[0], kpp[HW_]);
        }

    // ---- staging slots (iteration-invariant). granule idx = lane + 64k ----
    int goff[SPT];       // clamped (fy*HW_+fx), channel 0 base
    bool ok[SPT];        // granule inside image (else stage zeros)
    unsigned lslot[SPT]; // granule index in LDS (thread-linear, conflict-free)
#pragma unroll
    for (int k = 0; k < SPT; ++k) {
        const int idx = lane + NTHR * k;          // 0..383
        const int row = idx / WPX, px = idx - row * WPX;
        const int fy = y0b - 3 + row;
        const int fx = gx0 - 3 + px;
        const bool v = (idx < GRAN) &&
                       (unsigned)fy < (unsigned)HW_ && (unsigned)fx < (unsigned)HW_;
        const int fyc = fy < 0 ? 0 : (fy > HW_ - 1 ? HW_ - 1 : fy);
        const int fxc = fx < 0 ? 0 : (fx > HW_ - 1 ? HW_ - 1 : fx);
        goff[k] = fyc * HW_ + fxc;
        ok[k] = v;
        lslot[k] = (unsigned)idx;                 // pad granules absorb idle lanes
    }

    const float* Fb = F_ + (size_t)b * CHAN * HWPIX;

    // ---- prologue: issue loads for channel-octet 0 (8 planes per granule) ----
    float g[SPT][CG];
#pragma unroll
    for (int k = 0; k < SPT; ++k)
#pragma unroll
        for (int c = 0; c < CG; ++c)
            g[k][c] = Fb[goff[k] + c * HWPIX];

    float* ob = O_ + (size_t)b * CHAN * HWPIX + (size_t)y0 * HW_ + gx;

#pragma unroll 1
    for (int cq = 0; cq < NCQ; ++cq) {
        // ---- pack + write staged octet (thread-linear b128: conflict-free) ----
#pragma unroll
        for (int k = 0; k < SPT; ++k) {
            u32x4 w;
            w.x = ok[k] ? pkbf(g[k][0], g[k][1]) : 0u;
            w.y = ok[k] ? pkbf(g[k][2], g[k][3]) : 0u;
            w.z = ok[k] ? pkbf(g[k][4], g[k][5]) : 0u;
            w.w = ok[k] ? pkbf(g[k][6], g[k][7]) : 0u;
            lds[lslot[k]] = w;
        }

        // ---- issue next octet's loads; fly under compute (T14) ----
        if (cq + 1 < NCQ) {
            const float* Fp = Fb + (size_t)(cq + 1) * CG * HWPIX;
#pragma unroll
            for (int k = 0; k < SPT; ++k)
#pragma unroll
                for (int c = 0; c < CG; ++c)
                    g[k][c] = Fp[goff[k] + c * HWPIX];
        }

        // ---- compute: 8 window rows x 7 taps, 8 ch, y-pair ----
        float acc0[CG] = {0.f, 0.f, 0.f, 0.f, 0.f, 0.f, 0.f, 0.f};
        float acc1[CG] = {0.f, 0.f, 0.f, 0.f, 0.f, 0.f, 0.f, 0.f};
#pragma unroll
        for (int roff = 0; roff < 8; ++roff) {
            const int gb = (2 * ty + roff) * WPX + tx;
#pragma unroll
            for (int dx = 0; dx < KS; ++dx) {
                const u32x4 v = lds[gb + dx];
                float f[CG];
                f[0] = blo(v.x); f[1] = bhi(v.x);
                f[2] = blo(v.y); f[3] = bhi(v.y);
                f[4] = blo(v.z); f[5] = bhi(v.z);
                f[6] = blo(v.w); f[7] = bhi(v.w);
                if (roff < 7) {
                    const float t = blo(kp[roff * KS + dx]);       // y0, i=roff
#pragma unroll
                    for (int c = 0; c < CG; ++c) acc0[c] += f[c] * t;
                }
                if (roff > 0) {
                    const float t = bhi(kp[(roff - 1) * KS + dx]); // y0+1
#pragma unroll
                    for (int c = 0; c < CG; ++c) acc1[c] += f[c] * t;
                }
            }
        }

        // ---- stores: 32 lanes x 4B = one full 128B line per instr ----
        float* op = ob + (size_t)cq * CG * HWPIX;
#pragma unroll
        for (int c = 0; c < CG; ++c) {
            op[(size_t)c * HWPIX]       = acc0[c];
            op[(size_t)c * HWPIX + HW_] = acc1[c];
        }
    }
}

extern "C" void kernel_launch(void* const* d_in, const int* in_sizes, int n_in,
                              void* d_out, int out_size, void* d_ws, size_t ws_size,
                              hipStream_t stream) {
    const float* kernels  = (const float*)d_in[0];  // [4,7,7,256,256]
    const float* features = (const float*)d_in[1];  // [4,96,256,256]
    float* out = (float*)d_out;                     // [4,96,256,256]

    dim3 grid(2048);   // (8 xt) x (64 yt) x (4 b), decoded after XCD swizzle
    dim3 block(NTHR);
    svconv_v9<<<grid, block, 0, stream>>>(kernels, features, out);
}

// Round 10
// 85.447 us; speedup vs baseline: 1.8350x; 1.3303x over previous
//
#include <hip/hip_runtime.h>
#include <hip/hip_bf16.h>

// out[b,c,y,x] = sum_{i,j} f[b,c,y+i-3,x+j-3] * ker[b,i,j,y,x]
// 256-thread / 4-wave blocks, tile 32x16. Wave w owns y-rows y0b+4w..+3;
// thread = (tx 0..31, ty 0..1) -> one x-column, one y-pair, 8 channels/iter.
// LDS granule = 16B = 8 bf16 ch (y of one px row); window 22 rows x 38 px,
// DOUBLE-buffered (32 KB) -> one __syncthreads per channel-octet.
// Staging: thread-linear ds_write_b128 (conflict-free), coalesced dword loads.
// Taps: 49 u32 (bf16 y-pair packed) in VGPRs for the whole kernel.

#define BATCH 4
#define CHAN 96
#define HW_ 256
#define HWPIX 65536
#define KS 7
#define TW 32
#define TBY 16
#define NTHR 256
#define CG 8
#define NCQ (CHAN / CG)      // 12
#define WROWS 22             // TBY + 6
#define WPX 38               // TW + 6 (origin gx0-3)
#define GRAN (WROWS * WPX)   // 836
#define GRANP 1024           // per-buffer granule slots (pad absorbs idle lanes)
#define SPT 4                // ceil(GRAN/256)

typedef __attribute__((ext_vector_type(4))) unsigned u32x4;

static __device__ __forceinline__ unsigned pkbf(float a, float b) {
    union { __hip_bfloat162 h; unsigned u; } c;
    c.h = __float22bfloat162_rn(make_float2(a, b));
    return c.u;                 // lo = bf(a), hi = bf(b)
}
static __device__ __forceinline__ float blo(unsigned u) {
    union { unsigned v; float f; } c; c.v = u << 16; return c.f;
}
static __device__ __forceinline__ float bhi(unsigned u) {
    union { unsigned v; float f; } c; c.v = u & 0xffff0000u; return c.f;
}

__global__ __launch_bounds__(NTHR)
void svconv_v10(const float* __restrict__ K_, const float* __restrict__ F_,
                float* __restrict__ O_) {
    __shared__ u32x4 lds[2 * GRANP];   // 32768 B

    const int tid = threadIdx.x;
    const int xt = blockIdx.x, yt = blockIdx.y, b = blockIdx.z;
    const int gx0 = xt * TW, y0b = yt * TBY;
    const int wave = tid >> 6, lane = tid & 63;
    const int tx = lane & 31, ty = lane >> 5;
    const int gx = gx0 + tx;
    const int y0 = y0b + wave * 4 + 2 * ty;   // thread owns rows y0, y0+1
    const int wrow = wave * 4 + 2 * ty;       // window-row base for this thread

    // ---- taps: 49 u32, bf16 (y0, y0+1) pair per (i,j) ----
    unsigned kp[KS * KS];
#pragma unroll
    for (int i = 0; i < KS; ++i)
#pragma unroll
        for (int j = 0; j < KS; ++j) {
            const float* kpp =
                K_ + ((((size_t)b * KS + i) * KS + j) * HW_ + y0) * HW_ + gx;
            kp[i * KS + j] = pkbf(kpp[0], kpp[HW_]);
        }

    // ---- staging slots (iteration-invariant). granule idx = tid + 256k ----
    int goff[SPT];
    bool ok[SPT];
#pragma unroll
    for (int k = 0; k < SPT; ++k) {
        const int idx = tid + NTHR * k;           // 0..1023
        const int row = idx / WPX, px = idx - row * WPX;
        const int fy = y0b - 3 + row;
        const int fx = gx0 - 3 + px;
        ok[k] = (idx < GRAN) &&
                (unsigned)fy < (unsigned)HW_ && (unsigned)fx < (unsigned)HW_;
        const int fyc = fy < 0 ? 0 : (fy > HW_ - 1 ? HW_ - 1 : fy);
        const int fxc = fx < 0 ? 0 : (fx > HW_ - 1 ? HW_ - 1 : fx);
        goff[k] = fyc * HW_ + fxc;
    }

    const float* Fb = F_ + (size_t)b * CHAN * HWPIX;
    float g[SPT][CG];

    // issue: coalesced dword loads (lanes -> consecutive px) for octet cq
#define ISSUE(CQ) do {                                                    \
        const float* Fp_ = Fb + (size_t)(CQ) * CG * HWPIX;                \
        _Pragma("unroll")                                                 \
        for (int k_ = 0; k_ < SPT; ++k_)                                  \
            _Pragma("unroll")                                             \
            for (int c_ = 0; c_ < CG; ++c_)                               \
                g[k_][c_] = Fp_[goff[k_] + c_ * HWPIX];                   \
    } while (0)

    // commit: pack bf16 pairs, thread-linear b128 writes (conflict-free)
#define COMMIT(BUF) do {                                                  \
        u32x4* Lw_ = lds + (BUF) * GRANP;                                 \
        _Pragma("unroll")                                                 \
        for (int k_ = 0; k_ < SPT; ++k_) {                                \
            u32x4 w_;                                                     \
            w_.x = ok[k_] ? pkbf(g[k_][0], g[k_][1]) : 0u;                \
            w_.y = ok[k_] ? pkbf(g[k_][2], g[k_][3]) : 0u;                \
            w_.z = ok[k_] ? pkbf(g[k_][4], g[k_][5]) : 0u;                \
            w_.w = ok[k_] ? pkbf(g[k_][6], g[k_][7]) : 0u;                \
            Lw_[tid + NTHR * k_] = w_;                                    \
        }                                                                 \
    } while (0)

    // ---- prologue ----
    ISSUE(0);
    COMMIT(0);          // vmcnt wait on octet-0 loads
    ISSUE(1);           // flies under iter-0 compute
    __syncthreads();    // buf0 visible to all waves

    float* obb = O_ + (size_t)b * CHAN * HWPIX + (size_t)y0 * HW_ + gx;

#pragma unroll 2
    for (int cq = 0; cq < NCQ; ++cq) {
        // ---- compute from buf (cq&1): 8 window rows x 7 taps x 8 ch x y-pair
        const u32x4* L = lds + (cq & 1) * GRANP;
        float acc0[CG] = {0.f, 0.f, 0.f, 0.f, 0.f, 0.f, 0.f, 0.f};
        float acc1[CG] = {0.f, 0.f, 0.f, 0.f, 0.f, 0.f, 0.f, 0.f};
#pragma unroll
        for (int roff = 0; roff < 8; ++roff) {
            const int gb = (wrow + roff) * WPX + tx;
#pragma unroll
            for (int dx = 0; dx < KS; ++dx) {
                const u32x4 v = L[gb + dx];
                float f[CG];
                f[0] = blo(v.x); f[1] = bhi(v.x);
                f[2] = blo(v.y); f[3] = bhi(v.y);
                f[4] = blo(v.z); f[5] = bhi(v.z);
                f[6] = blo(v.w); f[7] = bhi(v.w);
                if (roff < 7) {
                    const float t = blo(kp[roff * KS + dx]);       // row y0
#pragma unroll
                    for (int c = 0; c < CG; ++c) acc0[c] += f[c] * t;
                }
                if (roff > 0) {
                    const float t = bhi(kp[(roff - 1) * KS + dx]); // row y0+1
#pragma unroll
                    for (int c = 0; c < CG; ++c) acc1[c] += f[c] * t;
                }
            }
        }

        // ---- stores: 32 lanes x 4B = full 128B lines ----
        float* op = obb + (size_t)cq * CG * HWPIX;
#pragma unroll
        for (int c = 0; c < CG; ++c) {
            op[(size_t)c * HWPIX]       = acc0[c];
            op[(size_t)c * HWPIX + HW_] = acc1[c];
        }

        // ---- pipeline: commit octet cq+1 to the other buffer (loads issued
        // one iteration ago -> vmcnt wait hidden), issue octet cq+2 ----
        if (cq + 1 < NCQ) {
            COMMIT((cq + 1) & 1);
            if (cq + 2 < NCQ) ISSUE(cq + 2);
            __syncthreads();   // all waves' commits visible before next reads
        }
    }
}

extern "C" void kernel_launch(void* const* d_in, const int* in_sizes, int n_in,
                              void* d_out, int out_size, void* d_ws, size_t ws_size,
                              hipStream_t stream) {
    const float* kernels  = (const float*)d_in[0];  // [4,7,7,256,256]
    const float* features = (const float*)d_in[1];  // [4,96,256,256]
    float* out = (float*)d_out;                     // [4,96,256,256]

    dim3 grid(HW_ / TW, HW_ / TBY, BATCH);  // (8, 16, 4) = 512 blocks
    dim3 block(NTHR);
    svconv_v10<<<grid, block, 0, stream>>>(kernels, features, out);
}

// Round 12
// 84.112 us; speedup vs baseline: 1.8641x; 1.0159x over previous
//
#include <hip/hip_runtime.h>
#include <hip/hip_bf16.h>

// out[b,c,y,x] = sum_{dy,dx} f[b,c,y+dy-3,x+dx-3] * ker[b,dy,dx,y,x]
// MFMA per 16-px strip: D[m=c][n=px] += A[m][k] * B[k][n];
//   A[m][k] = bf16(feat[c0+m, y+dy-3, gx0-4+nt*16+k])   (bf16 ring in LDS)
//   B[k][n] = bf16(ker[dy, k-n-1, y, gx0+nt*16+n]) for k-n-1 in [0,6], else 0
// XT=32: block = 256 thr = 4 waves (2 strips x 2 ch-halves); LDS 72.2 KB ->
// 2 independent blocks/CU (cross-block latency hiding). Two lgkm-only
// barriers per y keep all global prefetches in flight across iterations.
// R11 fix: idle ring-staging threads must NOT write (they clobbered slot 1919).

#define BATCH 4
#define CHAN 96
#define HW_ 256
#define HWPIX 65536
#define KS 7
#define XT 32
#define YT 16
#define NTHR 256
#define XPITCH 40                    // shorts per (row,c); 80 B, 16B-aligned
#define ROWSTRIDE (CHAN * XPITCH)    // 3840 shorts
#define RING_S (8 * ROWSTRIDE)       // 30720 shorts = 61440 B
#define NXP 20                       // x-pairs per (row,c)
#define RSLOTS (CHAN * NXP)          // 1920 u32 per row
#define RSPT 8
#define BT_K 24                      // stored k-dim (band max 22, pad 24)
#define BT_NROW (KS * BT_K)          // 168 shorts per n
#define BT_STRIP (16 * BT_NROW)      // 2688 shorts
#define BT_S (2 * BT_STRIP)          // 5376 shorts (2 strips, SINGLE buffer)
#define KVALS (KS * KS * XT)         // 1568
#define KSPT 7
#define LDS_BYTES ((RING_S + BT_S) * 2)   // 72192 B

typedef __attribute__((ext_vector_type(8))) short short8v;
typedef __attribute__((ext_vector_type(4))) float f32x4;

static __device__ __forceinline__ unsigned pkbf(float a, float b) {
    union { __hip_bfloat162 h; unsigned u; } c;
    c.h = __float22bfloat162_rn(make_float2(a, b));
    return c.u;                 // lo = bf(a), hi = bf(b)
}
static __device__ __forceinline__ short bfbits(float x) {
    union { __hip_bfloat16 h; short s; } c;
    c.h = __float2bfloat16(x);
    return c.s;
}

// drain LDS ops only; global loads/stores stay in flight across the barrier
#define LDS_BARRIER() asm volatile("s_waitcnt lgkmcnt(0)\ns_barrier" ::: "memory")

__global__ __launch_bounds__(NTHR)
void svconv_v12(const float* __restrict__ K_, const float* __restrict__ F_,
                float* __restrict__ O_) {
    extern __shared__ short lds[];           // ring | BT
    unsigned* ring32 = (unsigned*)lds;
    short* BT = lds + RING_S;

    const int tid = threadIdx.x;
    const int xt = blockIdx.x, yt = blockIdx.y, b = blockIdx.z;
    const int gx0 = xt * XT, gy0 = yt * YT;
    const int wave = tid >> 6, lane = tid & 63;
    const int nt = wave & 1, ch = wave >> 1;   // strip 0..1, c-half 0..1
    const int n = lane & 15, kb = lane >> 4;   // frag col / k-group

    // ---- ring staging slots (iteration-invariant): u32 x-pairs ----
    int rgo[RSPT]; unsigned rls[RSPT]; unsigned rm[RSPT]; bool rv[RSPT];
#pragma unroll
    for (int k = 0; k < RSPT; ++k) {
        const int idx = tid + NTHR * k;
        const bool valid = idx < RSLOTS;          // k==7 batch is partial
        const int c = valid ? idx / NXP : 0;
        const int xi = valid ? idx - c * NXP : 0;
        const int fx0 = gx0 - 4 + 2 * xi;
        const int fxc = fx0 < 0 ? 0 : (fx0 > HW_ - 2 ? HW_ - 2 : fx0);  // even
        rgo[k] = c * HWPIX + fxc;
        rls[k] = (unsigned)(c * NXP + xi);
        unsigned m0 = ((unsigned)fx0 < (unsigned)HW_) ? 0xFFFFu : 0u;
        unsigned m1 = ((unsigned)(fx0 + 1) < (unsigned)HW_) ? 0xFFFF0000u : 0u;
        rm[k] = m0 | m1;
        rv[k] = valid;
    }
    const float* Fb = F_ + (size_t)b * CHAN * HWPIX;

    // ---- BT band staging slots: coalesced K source, scattered b16 writes ----
    int kg[KSPT], kl[KSPT];
#pragma unroll
    for (int i = 0; i < KSPT; ++i) {
        const int idx = tid + NTHR * i;
        if (idx < KVALS) {
            const int dydx = idx >> 5, xl = idx & 31;
            const int dy = dydx / KS, dx = dydx - KS * dy;
            const int sn = xl & 15, snt = xl >> 4;
            kg[i] = dydx * HWPIX + gx0 + xl;
            kl[i] = snt * BT_STRIP + sn * BT_NROW + dy * BT_K + (sn + dx + 1);
        } else { kg[i] = 0; kl[i] = -1; }
    }
    const float* Kb = K_ + (size_t)b * KS * KS * HWPIX;

    // ---- zero BT once (non-band slots must stay 0 forever) ----
    {
        unsigned* bt32 = (unsigned*)BT;       // BT_S/2 = 2688 u32
#pragma unroll
        for (int i = 0; i < 11; ++i) {
            const int idx = tid + NTHR * i;
            if (idx < BT_S / 2) bt32[idx] = 0u;
        }
    }

    // ---- prologue: ring rows gy0-3..gy0+3 (OOB rows -> zeros) ----
    for (int r = -3; r <= 3; ++r) {
        const int yr = gy0 + r;
        const bool yok = (unsigned)yr < (unsigned)HW_;
        const int yrc = yr < 0 ? 0 : (yr > HW_ - 1 ? HW_ - 1 : yr);
        const unsigned sbase = (unsigned)((yr & 7) * RSLOTS);
        float2 v[RSPT];
#pragma unroll
        for (int k = 0; k < RSPT; ++k)
            v[k] = *(const float2*)(Fb + rgo[k] + (size_t)yrc * HW_);
#pragma unroll
        for (int k = 0; k < RSPT; ++k) {
            unsigned w = pkbf(v[k].x, v[k].y) & rm[k];
            if (!yok) w = 0u;
            if (rv[k]) ring32[sbase + rls[k]] = w;
        }
    }

    LDS_BARRIER();   // BT zeros visible before band writes

    // ---- prologue: BT bands for row gy0 ----
    {
        float kr0[KSPT];
#pragma unroll
        for (int i = 0; i < KSPT; ++i)
            kr0[i] = (kl[i] >= 0) ? Kb[kg[i] + (size_t)gy0 * HW_] : 0.f;
#pragma unroll
        for (int i = 0; i < KSPT; ++i)
            if (kl[i] >= 0) BT[kl[i]] = bfbits(kr0[i]);
    }

    // ---- prefetch: ring row gy0+4, K row gy0+1 ----
    float2 rr[RSPT];
    float kr[KSPT];
#pragma unroll
    for (int k = 0; k < RSPT; ++k)
        rr[k] = *(const float2*)(Fb + rgo[k] + (size_t)(gy0 + 4) * HW_);
#pragma unroll
    for (int i = 0; i < KSPT; ++i)
        kr[i] = (kl[i] >= 0) ? Kb[kg[i] + (size_t)(gy0 + 1) * HW_] : 0.f;

    const int kcl8 = (kb == 3) ? 0 : kb * 8;   // kb=3 supplies zero B; dummy A
    const short* btp = BT + nt * BT_STRIP + n * BT_NROW + kb * 8;
    const int arow = (ch * 48 + n) * XPITCH + nt * 16 + kcl8;
    float* ob = O_ + ((size_t)(b * CHAN + ch * 48 + kb * 4)) * HWPIX
              + gx0 + nt * 16 + n;
    const short8v bzero = {0, 0, 0, 0, 0, 0, 0, 0};

#pragma unroll 1
    for (int t = 0; t < YT; ++t) {
        const int y = gy0 + t;
        LDS_BARRIER();   // A: BT[y] + ring rows visible; prefetches in flight

        // B fragments (7x ds_read_b128, 16B-aligned)
        short8v b0, b1, b2, b3, b4, b5, b6;
        if (kb < 3) {
            b0 = *(const short8v*)(btp);
            b1 = *(const short8v*)(btp + 1 * BT_K);
            b2 = *(const short8v*)(btp + 2 * BT_K);
            b3 = *(const short8v*)(btp + 3 * BT_K);
            b4 = *(const short8v*)(btp + 4 * BT_K);
            b5 = *(const short8v*)(btp + 5 * BT_K);
            b6 = *(const short8v*)(btp + 6 * BT_K);
        } else {
            b0 = bzero; b1 = bzero; b2 = bzero; b3 = bzero;
            b4 = bzero; b5 = bzero; b6 = bzero;
        }

        // A reads + MFMA: 3 c-tiles, dy-chained accumulators
        f32x4 acc0 = {0,0,0,0}, acc1 = {0,0,0,0}, acc2 = {0,0,0,0};
#pragma unroll
        for (int dy = 0; dy < KS; ++dy) {
            const short8v bf = dy == 0 ? b0 : dy == 1 ? b1 : dy == 2 ? b2 :
                               dy == 3 ? b3 : dy == 4 ? b4 : dy == 5 ? b5 : b6;
            const short* ap = lds + ((y + dy + 5) & 7) * ROWSTRIDE + arow;
            acc0 = __builtin_amdgcn_mfma_f32_16x16x32_bf16(*(const short8v*)(ap), bf, acc0, 0, 0, 0);
            acc1 = __builtin_amdgcn_mfma_f32_16x16x32_bf16(*(const short8v*)(ap + 16 * XPITCH), bf, acc1, 0, 0, 0);
            acc2 = __builtin_amdgcn_mfma_f32_16x16x32_bf16(*(const short8v*)(ap + 32 * XPITCH), bf, acc2, 0, 0, 0);
        }

        // stores: D col = n (px), row = kb*4+r (channel)
        {
            float* op = ob + (size_t)y * HW_;
#pragma unroll
            for (int r = 0; r < 4; ++r) {
                op[(size_t)r * HWPIX]        = acc0[r];
                op[(size_t)(16 + r) * HWPIX] = acc1[r];
                op[(size_t)(32 + r) * HWPIX] = acc2[r];
            }
        }

        LDS_BARRIER();   // B: all LDS reads drained; safe to overwrite BT/ring

        if (t < YT - 1) {
            // commit ring row y+4 (zeros when OOB); vmcnt waits land here,
            // one full iteration after issue
            const bool yok = (y + 4) < HW_;
            const unsigned sbase = (unsigned)(((y + 4) & 7) * RSLOTS);
#pragma unroll
            for (int k = 0; k < RSPT; ++k) {
                unsigned w = pkbf(rr[k].x, rr[k].y) & rm[k];
                if (!yok) w = 0u;
                if (rv[k]) ring32[sbase + rls[k]] = w;
            }
            // BT bands for row y+1 (in place; protected by barrier B/A pair)
#pragma unroll
            for (int i = 0; i < KSPT; ++i)
                if (kl[i] >= 0) BT[kl[i]] = bfbits(kr[i]);
        }

        if (t < YT - 2) {
            // issue next prefetches; they stay in flight across both barriers
            const int yr = y + 5;
            const int yrc = yr > HW_ - 1 ? HW_ - 1 : yr;   // commit masks OOB
#pragma unroll
            for (int k = 0; k < RSPT; ++k)
                rr[k] = *(const float2*)(Fb + rgo[k] + (size_t)yrc * HW_);
#pragma unroll
            for (int i = 0; i < KSPT; ++i)
                kr[i] = (kl[i] >= 0) ? Kb[kg[i] + (size_t)(y + 2) * HW_] : 0.f;
        }
    }
}

extern "C" void kernel_launch(void* const* d_in, const int* in_sizes, int n_in,
                              void* d_out, int out_size, void* d_ws, size_t ws_size,
                              hipStream_t stream) {
    const float* kernels  = (const float*)d_in[0];  // [4,7,7,256,256]
    const float* features = (const float*)d_in[1];  // [4,96,256,256]
    float* out = (float*)d_out;                     // [4,96,256,256]

    hipFuncSetAttribute(reinterpret_cast<const void*>(&svconv_v12),
                        hipFuncAttributeMaxDynamicSharedMemorySize, LDS_BYTES);

    dim3 grid(HW_ / XT, HW_ / YT, BATCH);  // (8, 16, 4) = 512 blocks = 2/CU
    dim3 block(NTHR);
    svconv_v12<<<grid, block, LDS_BYTES, stream>>>(kernels, features, out);
}